// Round 1
// baseline (801.599 us; speedup 1.0000x reference)
//
#include <hip/hip_runtime.h>

#define BATCH 2
#define NN 8192
#define DD 256
#define BK 64

typedef __attribute__((ext_vector_type(8))) short bf16x8;   // 8 bf16 = 4 VGPR
typedef __attribute__((ext_vector_type(4))) float f32x4;

__device__ __forceinline__ unsigned short f2bf(float f) {
    unsigned u = __builtin_bit_cast(unsigned, f);
    u += 0x7fffu + ((u >> 16) & 1u);          // RNE
    return (unsigned short)(u >> 16);
}

// ---- kernel 1: per-row logmap0 scale = artanh(||x||)/||x|| ----
__global__ void k_logmap_scale(const float* __restrict__ x, float* __restrict__ scale) {
    int row = blockIdx.x;                 // 0 .. B*N-1
    int lane = threadIdx.x;               // 0..63
    const float4* xr = (const float4*)(x + (size_t)row * DD);
    float4 v = xr[lane];
    float s = v.x * v.x + v.y * v.y + v.z * v.z + v.w * v.w;
#pragma unroll
    for (int m = 1; m < 64; m <<= 1) s += __shfl_xor(s, m, 64);
    if (lane == 0) {
        float n = sqrtf(s);
        n = fmaxf(n, 1e-15f);
        float z = fminf(n, 1.0f - 1e-7f);
        float at = 0.5f * logf((1.0f + z) / (1.0f - z));   // artanh
        scale[row] = at / n;
    }
}

// ---- kernel 2: scaled transpose to bf16, layout xtf[b][kb][d][nn] (kb=n/64, nn=n%64) ----
__global__ void k_transpose(const float* __restrict__ x, const float* __restrict__ scale,
                            unsigned short* __restrict__ xtf) {
    __shared__ __align__(16) unsigned short T[DD][72];     // [d][r], stride 72 breaks conflicts
    int bid = blockIdx.x;                  // 0..255
    int b = bid >> 7, kb = bid & 127;
    int bn0 = b * NN + kb * 64;
    int t = threadIdx.x;
    int r = t >> 2, cc = t & 3;            // row-in-tile, 64-col chunk
    float sc = scale[bn0 + r];
    const float4* rp = (const float4*)(x + (size_t)(bn0 + r) * DD + cc * 64);
#pragma unroll
    for (int j4 = 0; j4 < 16; ++j4) {
        float4 v = rp[j4];
        int d = cc * 64 + j4 * 4;
        T[d + 0][r] = f2bf(v.x * sc);
        T[d + 1][r] = f2bf(v.y * sc);
        T[d + 2][r] = f2bf(v.z * sc);
        T[d + 3][r] = f2bf(v.w * sc);
    }
    __syncthreads();
    unsigned short* outp = xtf + (size_t)(b * 128 + kb) * DD * 64;
    int dd = t >> 3, ccc = t & 7;
#pragma unroll
    for (int p = 0; p < 8; ++p) {
        int d = dd + 32 * p;
        bf16x8 val = *(const bf16x8*)&T[d][ccc * 8];
        *(bf16x8*)(outp + (size_t)d * 64 + ccc * 8) = val;   // fully coalesced 4KB/instr
    }
}

// ---- kernel 3: GEMM (adj fp32 -> bf16 MFMA) + fused expmap0/project epilogue ----
// block: 256 thr = 4 waves; tile 64 rows x 256 cols (full D -> row norm is block-local)
__global__ __launch_bounds__(256, 1) void k_gemm(const float* __restrict__ adj,
                                                 const unsigned short* __restrict__ xtf,
                                                 float* __restrict__ out) {
    __shared__ __align__(16) unsigned short A_lds[64][72];  // stride 72: 2-way (free) frag reads
    __shared__ float red[4][64];
    __shared__ float rowscale[64];

    int bid = blockIdx.x;
    // XCD swizzle: XCDs 0-3 -> batch 0, XCDs 4-7 -> batch 1 (xt[b] fits one XCD's 4MiB L2)
    int xcd = bid & 7;
    int b = xcd >> 2;
    int mtile = ((bid >> 3) << 2) | (xcd & 3);   // bijective over 0..127
    int m0 = mtile * 64;

    int t = threadIdx.x;
    int w = t >> 6, lane = t & 63, c = lane & 15, q = lane >> 4;

    // A staging: thread loads float4 at (row = i*16 + t>>4, col4 = t&15) -> coalesced 256B rows
    int ar = t >> 4;
    int ac4 = t & 15;
    const float* abase = adj + (size_t)b * NN * NN + (size_t)(m0 + ar) * NN + ac4 * 4;

    // B fragments straight from global (L2-resident): lane holds xt^T[col][k..k+8)
    const unsigned short* xbase = xtf + (size_t)b * 128 * DD * 64
                                + (size_t)(w * 64 + c) * 64 + q * 8;

    f32x4 acc[4][4];
#pragma unroll
    for (int i = 0; i < 4; ++i)
#pragma unroll
        for (int j = 0; j < 4; ++j)
#pragma unroll
            for (int rg = 0; rg < 4; ++rg) acc[i][j][rg] = 0.0f;

    float4 av[4];
    bf16x8 bcur[4][2], bnxt[4][2];

    // prologue: kb = 0
#pragma unroll
    for (int i = 0; i < 4; ++i)
        av[i] = *(const float4*)(abase + (size_t)(i * 16) * NN);
#pragma unroll
    for (int nt = 0; nt < 4; ++nt)
#pragma unroll
        for (int kk = 0; kk < 2; ++kk)
            bcur[nt][kk] = *(const bf16x8*)(xbase + nt * 16 * 64 + kk * 32);

    for (int kb = 0; kb < 128; ++kb) {
        // convert + store A regs -> LDS
#pragma unroll
        for (int i = 0; i < 4; ++i) {
            ushort4 pk;
            pk.x = f2bf(av[i].x); pk.y = f2bf(av[i].y);
            pk.z = f2bf(av[i].z); pk.w = f2bf(av[i].w);
            *(ushort4*)&A_lds[ar + i * 16][ac4 * 4] = pk;
        }
        __syncthreads();

        if (kb + 1 < 128) {           // register prefetch of next K-tile (latency hides under MFMA)
            const float* ab = abase + (size_t)(kb + 1) * BK;
#pragma unroll
            for (int i = 0; i < 4; ++i)
                av[i] = *(const float4*)(ab + (size_t)(i * 16) * NN);
            const unsigned short* xb = xbase + (size_t)(kb + 1) * DD * 64;
#pragma unroll
            for (int nt = 0; nt < 4; ++nt)
#pragma unroll
                for (int kk = 0; kk < 2; ++kk)
                    bnxt[nt][kk] = *(const bf16x8*)(xb + nt * 16 * 64 + kk * 32);
        }

#pragma unroll
        for (int kk = 0; kk < 2; ++kk) {
            bf16x8 af[4];
#pragma unroll
            for (int mt = 0; mt < 4; ++mt)
                af[mt] = *(const bf16x8*)&A_lds[mt * 16 + c][kk * 32 + q * 8];
#pragma unroll
            for (int mt = 0; mt < 4; ++mt)
#pragma unroll
                for (int nt = 0; nt < 4; ++nt)
                    acc[mt][nt] = __builtin_amdgcn_mfma_f32_16x16x32_bf16(
                        af[mt], bcur[nt][kk], acc[mt][nt], 0, 0, 0);
        }
        __syncthreads();

        if (kb + 1 < 128) {
#pragma unroll
            for (int nt = 0; nt < 4; ++nt)
#pragma unroll
                for (int kk = 0; kk < 2; ++kk)
                    bcur[nt][kk] = bnxt[nt][kk];
        }
    }

    // ---- epilogue: row norms over full D, then out = min(tanh(n), 1-4e-3)/n * u ----
    // C/D layout: col = lane&15 (=c), row-in-16 = q*4 + reg
    float s[4][4];
#pragma unroll
    for (int mt = 0; mt < 4; ++mt)
#pragma unroll
        for (int rg = 0; rg < 4; ++rg) {
            float v = acc[mt][0][rg] * acc[mt][0][rg] + acc[mt][1][rg] * acc[mt][1][rg]
                    + acc[mt][2][rg] * acc[mt][2][rg] + acc[mt][3][rg] * acc[mt][3][rg];
            v += __shfl_xor(v, 1, 64);
            v += __shfl_xor(v, 2, 64);
            v += __shfl_xor(v, 4, 64);
            v += __shfl_xor(v, 8, 64);    // sum over the wave's 64 cols
            s[mt][rg] = v;
        }
#pragma unroll
    for (int mt = 0; mt < 4; ++mt)
#pragma unroll
        for (int rg = 0; rg < 4; ++rg)
            if (c == mt * 4 + rg)
                red[w][mt * 16 + q * 4 + rg] = s[mt][rg];
    __syncthreads();
    if (t < 64) {
        float tot = red[0][t] + red[1][t] + red[2][t] + red[3][t];
        float n = sqrtf(tot);
        n = fmaxf(n, 1e-15f);
        float th = tanhf(n);
        rowscale[t] = fminf(th, 1.0f - 4e-3f) / n;   // expmap0 + project fused
    }
    __syncthreads();

    float* obase = out + ((size_t)b * NN + m0) * DD + w * 64 + c;
#pragma unroll
    for (int mt = 0; mt < 4; ++mt)
#pragma unroll
        for (int rg = 0; rg < 4; ++rg) {
            float rs = rowscale[mt * 16 + q * 4 + rg];
            float* orow = obase + (size_t)(mt * 16 + q * 4 + rg) * DD;
#pragma unroll
            for (int nt = 0; nt < 4; ++nt)
                orow[nt * 16] = acc[mt][nt][rg] * rs;
        }
}

extern "C" void kernel_launch(void* const* d_in, const int* in_sizes, int n_in,
                              void* d_out, int out_size, void* d_ws, size_t ws_size,
                              hipStream_t stream) {
    const float* x   = (const float*)d_in[0];   // [2, 8192, 256] fp32
    const float* adj = (const float*)d_in[1];   // [2, 8192, 8192] fp32
    float* out = (float*)d_out;                 // [2, 8192, 256] fp32

    unsigned short* xtf = (unsigned short*)d_ws;                        // 8 MiB bf16 xt^T tiles
    float* scale = (float*)((char*)d_ws + (size_t)BATCH * 128 * DD * 64 * 2);  // 64 KiB

    k_logmap_scale<<<BATCH * NN, 64, 0, stream>>>(x, scale);
    k_transpose<<<BATCH * 128, 256, 0, stream>>>(x, scale, xtf);
    k_gemm<<<256, 256, 0, stream>>>(adj, xtf, out);
}